// Round 1
// baseline (1328.427 us; speedup 1.0000x reference)
//
#include <hip/hip_runtime.h>

#define N_NODES 100000
#define D_IN 32
#define H 64
#define EPS 1e-5f

// Wave-per-node MLP: lane j owns output channel j. Weight columns W1[:,j],
// W2[:,j] are held in VGPRs (96 regs), loaded once per wave. Inner products
// use __shfl broadcasts (constant lane after unroll -> v_readlane). LN via
// __shfl_xor butterfly across the 64-lane wave.
__global__ __launch_bounds__(256) void mlp_kernel(
    const float* __restrict__ x,
    const float* __restrict__ W1, const float* __restrict__ b1,
    const float* __restrict__ g1, const float* __restrict__ be1,
    const float* __restrict__ W2, const float* __restrict__ b2,
    const float* __restrict__ g2, const float* __restrict__ be2,
    float* __restrict__ h, float* __restrict__ out)
{
    const int lane   = threadIdx.x & 63;
    const int wave   = blockIdx.x * (blockDim.x >> 6) + (threadIdx.x >> 6);
    const int nwaves = gridDim.x * (blockDim.x >> 6);

    // Per-lane weight columns (lane-consecutive -> coalesced loads, reused
    // across all nodes this wave processes).
    float w1c[D_IN];
#pragma unroll
    for (int k = 0; k < D_IN; ++k) w1c[k] = W1[k * H + lane];
    float w2c[H];
#pragma unroll
    for (int k = 0; k < H; ++k) w2c[k] = W2[k * H + lane];
    const float b1v = b1[lane], g1v = g1[lane], be1v = be1[lane];
    const float b2v = b2[lane], g2v = g2[lane], be2v = be2[lane];

    for (int node = wave; node < N_NODES; node += nwaves) {
        // lanes 0..31 hold x[node][lane]
        float xv = (lane < D_IN) ? x[node * D_IN + lane] : 0.0f;

        // ---- layer 1: y = x @ W1 + b1 ----
        float y = b1v;
#pragma unroll
        for (int k = 0; k < D_IN; ++k)
            y += __shfl(xv, k) * w1c[k];

        // ---- LN1 + ReLU ----
        float s = y, ss = y * y;
#pragma unroll
        for (int m = 1; m < 64; m <<= 1) {
            s  += __shfl_xor(s, m);
            ss += __shfl_xor(ss, m);
        }
        float mu  = s * (1.0f / 64.0f);
        float var = ss * (1.0f / 64.0f) - mu * mu;
        float hv  = (y - mu) * rsqrtf(var + EPS) * g1v + be1v;
        hv = fmaxf(hv, 0.0f);

        // ---- layer 2: y2 = h1 @ W2 + b2 ----
        float y2 = b2v;
#pragma unroll
        for (int k = 0; k < H; ++k)
            y2 += __shfl(hv, k) * w2c[k];

        // ---- LN2 + ReLU ----
        float s2 = y2, ss2 = y2 * y2;
#pragma unroll
        for (int m = 1; m < 64; m <<= 1) {
            s2  += __shfl_xor(s2, m);
            ss2 += __shfl_xor(ss2, m);
        }
        float mu2  = s2 * (1.0f / 64.0f);
        float var2 = ss2 * (1.0f / 64.0f) - mu2 * mu2;
        float hv2  = (y2 - mu2) * rsqrtf(var2 + EPS) * g2v + be2v;
        hv2 = fmaxf(hv2, 0.0f);

        // coalesced 256B stores per wave
        h[node * H + lane]   = hv2;
        out[node * H + lane] = hv2;  // out starts as h; edge kernel adds aggr
    }
}

// 16 threads per edge, 4 channels each (float4 gather, 4 scalar atomics).
__global__ __launch_bounds__(256) void edge_kernel(
    const int* __restrict__ ei, const float* __restrict__ h,
    float* __restrict__ out, int E)
{
    long long tid = (long long)blockIdx.x * blockDim.x + threadIdx.x;
    int e = (int)(tid >> 4);
    if (e >= E) return;
    int g = (int)(tid & 15);

    int row = ei[e];       // destination (segment id)
    int col = ei[E + e];   // source node

    const float4* h4 = (const float4*)h;
    float4 v = h4[(long long)col * 16 + g];
    float* dst = out + (long long)row * 64 + g * 4;
    atomicAdd(dst + 0, v.x);
    atomicAdd(dst + 1, v.y);
    atomicAdd(dst + 2, v.z);
    atomicAdd(dst + 3, v.w);
}

extern "C" void kernel_launch(void* const* d_in, const int* in_sizes, int n_in,
                              void* d_out, int out_size, void* d_ws, size_t ws_size,
                              hipStream_t stream)
{
    const float* x   = (const float*)d_in[0];
    const int*   ei  = (const int*)d_in[1];
    const float* W1  = (const float*)d_in[2];
    const float* b1  = (const float*)d_in[3];
    const float* g1  = (const float*)d_in[4];
    const float* be1 = (const float*)d_in[5];
    const float* W2  = (const float*)d_in[6];
    const float* b2  = (const float*)d_in[7];
    const float* g2  = (const float*)d_in[8];
    const float* be2 = (const float*)d_in[9];

    float* out = (float*)d_out;
    float* h   = (float*)d_ws;  // 100000*64*4 = 25.6 MB scratch

    const int E = in_sizes[1] / 2;

    // 1024 blocks * 4 waves = 4096 waves (~4/SIMD), each ~24 nodes.
    mlp_kernel<<<1024, 256, 0, stream>>>(x, W1, b1, g1, be1,
                                         W2, b2, g2, be2, h, out);

    long long threads = (long long)E * 16;
    int blocks = (int)((threads + 255) / 256);
    edge_kernel<<<blocks, 256, 0, stream>>>(ei, h, out, E);
}

// Round 2
// 326.661 us; speedup vs baseline: 4.0667x; 4.0667x over previous
//
#include <hip/hip_runtime.h>

#define N_NODES 100000
#define D_IN 32
#define H 64
#define EPS 1e-5f
#define CAP 32   // bucket capacity per destination node; Poisson(12.5) => P(deg>32)~7e-7

// ---------------- zero the per-node edge counters ----------------
__global__ __launch_bounds__(256) void zero_kernel(int* __restrict__ cnt, int n)
{
    int i = blockIdx.x * blockDim.x + threadIdx.x;
    if (i < n) cnt[i] = 0;
}

// ---------------- node MLP: thread-per-node, no cross-lane ops ----------------
// Each thread owns one node. Weight reads are wave-uniform (compiler can use
// SMEM / broadcast loads); LayerNorm is per-lane arithmetic. Zero DS ops.
__global__ __launch_bounds__(256) void mlp_kernel(
    const float* __restrict__ x,
    const float* __restrict__ W1, const float* __restrict__ b1,
    const float* __restrict__ g1, const float* __restrict__ be1,
    const float* __restrict__ W2, const float* __restrict__ b2,
    const float* __restrict__ g2, const float* __restrict__ be2,
    float* __restrict__ h, float* __restrict__ out)
{
    int node = blockIdx.x * blockDim.x + threadIdx.x;
    if (node >= N_NODES) return;

    // ---- load x[32] (per-lane contiguous; 8KB/wave region, L1-friendly) ----
    float xr[D_IN];
    {
        const float4* xp = (const float4*)(x + (long long)node * D_IN);
#pragma unroll
        for (int i = 0; i < D_IN / 4; ++i) {
            float4 v = xp[i];
            xr[4*i+0] = v.x; xr[4*i+1] = v.y; xr[4*i+2] = v.z; xr[4*i+3] = v.w;
        }
    }

    // ---- layer 1: h1 = x @ W1 + b1 (k-outer: each W1 row read once/wave) ----
    float h1[H];
#pragma unroll
    for (int jb = 0; jb < H / 4; ++jb) {
        float4 b = *(const float4*)(b1 + jb * 4);
        h1[4*jb+0] = b.x; h1[4*jb+1] = b.y; h1[4*jb+2] = b.z; h1[4*jb+3] = b.w;
    }
#pragma unroll
    for (int k = 0; k < D_IN; ++k) {
        float xk = xr[k];
#pragma unroll
        for (int jb = 0; jb < H / 4; ++jb) {
            float4 w = *(const float4*)(W1 + k * H + jb * 4);
            h1[4*jb+0] += xk * w.x; h1[4*jb+1] += xk * w.y;
            h1[4*jb+2] += xk * w.z; h1[4*jb+3] += xk * w.w;
        }
    }

    // ---- LN1 + ReLU (per-lane, 4 partial sums for ILP) ----
    {
        float s0=0,s1=0,s2=0,s3=0, q0=0,q1=0,q2=0,q3=0;
#pragma unroll
        for (int j = 0; j < H; j += 4) {
            s0 += h1[j+0]; s1 += h1[j+1]; s2 += h1[j+2]; s3 += h1[j+3];
            q0 += h1[j+0]*h1[j+0]; q1 += h1[j+1]*h1[j+1];
            q2 += h1[j+2]*h1[j+2]; q3 += h1[j+3]*h1[j+3];
        }
        float mu  = (s0+s1+s2+s3) * (1.0f / H);
        float var = (q0+q1+q2+q3) * (1.0f / H) - mu * mu;
        float rs  = rsqrtf(var + EPS);
#pragma unroll
        for (int jb = 0; jb < H / 4; ++jb) {
            float4 g = *(const float4*)(g1 + jb * 4);
            float4 be = *(const float4*)(be1 + jb * 4);
            h1[4*jb+0] = fmaxf((h1[4*jb+0]-mu)*rs*g.x + be.x, 0.0f);
            h1[4*jb+1] = fmaxf((h1[4*jb+1]-mu)*rs*g.y + be.y, 0.0f);
            h1[4*jb+2] = fmaxf((h1[4*jb+2]-mu)*rs*g.z + be.z, 0.0f);
            h1[4*jb+3] = fmaxf((h1[4*jb+3]-mu)*rs*g.w + be.w, 0.0f);
        }
    }

    // ---- layer 2: h2 = h1 @ W2 + b2 ----
    float h2[H];
#pragma unroll
    for (int jb = 0; jb < H / 4; ++jb) {
        float4 b = *(const float4*)(b2 + jb * 4);
        h2[4*jb+0] = b.x; h2[4*jb+1] = b.y; h2[4*jb+2] = b.z; h2[4*jb+3] = b.w;
    }
#pragma unroll
    for (int k = 0; k < H; ++k) {
        float hk = h1[k];
#pragma unroll
        for (int jb = 0; jb < H / 4; ++jb) {
            float4 w = *(const float4*)(W2 + k * H + jb * 4);
            h2[4*jb+0] += hk * w.x; h2[4*jb+1] += hk * w.y;
            h2[4*jb+2] += hk * w.z; h2[4*jb+3] += hk * w.w;
        }
    }

    // ---- LN2 + ReLU + store ----
    {
        float s0=0,s1=0,s2=0,s3=0, q0=0,q1=0,q2=0,q3=0;
#pragma unroll
        for (int j = 0; j < H; j += 4) {
            s0 += h2[j+0]; s1 += h2[j+1]; s2 += h2[j+2]; s3 += h2[j+3];
            q0 += h2[j+0]*h2[j+0]; q1 += h2[j+1]*h2[j+1];
            q2 += h2[j+2]*h2[j+2]; q3 += h2[j+3]*h2[j+3];
        }
        float mu  = (s0+s1+s2+s3) * (1.0f / H);
        float var = (q0+q1+q2+q3) * (1.0f / H) - mu * mu;
        float rs  = rsqrtf(var + EPS);

        float* hp = h   + (long long)node * H;
        float* op = out + (long long)node * H;
#pragma unroll
        for (int jb = 0; jb < H / 4; ++jb) {
            float4 g = *(const float4*)(g2 + jb * 4);
            float4 be = *(const float4*)(be2 + jb * 4);
            float4 v;
            v.x = fmaxf((h2[4*jb+0]-mu)*rs*g.x + be.x, 0.0f);
            v.y = fmaxf((h2[4*jb+1]-mu)*rs*g.y + be.y, 0.0f);
            v.z = fmaxf((h2[4*jb+2]-mu)*rs*g.z + be.z, 0.0f);
            v.w = fmaxf((h2[4*jb+3]-mu)*rs*g.w + be.w, 0.0f);
            *(float4*)(hp + 4*jb) = v;
            *(float4*)(op + 4*jb) = v;   // out starts as h; aggregation adds on top
        }
    }
}

// ---------------- edge scatter: build per-destination buckets ----------------
// One thread per edge: append col to row's bucket via int atomic cursor.
// Overflow (deg > CAP, ~never for Poisson(12.5)) falls back to direct
// float atomics into out — keeps exact correctness without a scan.
__global__ __launch_bounds__(256) void scatter_kernel(
    const int* __restrict__ ei, const float* __restrict__ h,
    int* __restrict__ cnt, int* __restrict__ bkt,
    float* __restrict__ out, int E)
{
    int e = blockIdx.x * blockDim.x + threadIdx.x;
    if (e >= E) return;
    int row = ei[e];
    int col = ei[E + e];
    int pos = atomicAdd(&cnt[row], 1);
    if (pos < CAP) {
        bkt[row * CAP + pos] = col;
    } else {
        const float* hp = h + (long long)col * H;
        float* op = out + (long long)row * H;
        for (int c = 0; c < H; ++c) atomicAdd(op + c, hp[c]);
    }
}

// ---------------- pull aggregation: wave per node, lane = channel ----------------
__global__ __launch_bounds__(256) void aggr_kernel(
    const int* __restrict__ cnt, const int* __restrict__ bkt,
    const float* __restrict__ h, float* __restrict__ out)
{
    int lane = threadIdx.x & 63;
    int node = blockIdx.x * (blockDim.x >> 6) + (threadIdx.x >> 6);
    if (node >= N_NODES) return;

    int m = cnt[node];
    if (m > CAP) m = CAP;
    const int* b = bkt + node * CAP;

    float acc = 0.0f;
    int i = 0;
    for (; i + 1 < m; i += 2) {       // 2-way to overlap dependent gathers
        int c0 = b[i], c1 = b[i + 1];
        float v0 = h[(long long)c0 * H + lane];
        float v1 = h[(long long)c1 * H + lane];
        acc += v0; acc += v1;
    }
    if (i < m) acc += h[(long long)b[i] * H + lane];

    out[(long long)node * H + lane] += acc;
}

extern "C" void kernel_launch(void* const* d_in, const int* in_sizes, int n_in,
                              void* d_out, int out_size, void* d_ws, size_t ws_size,
                              hipStream_t stream)
{
    const float* x   = (const float*)d_in[0];
    const int*   ei  = (const int*)d_in[1];
    const float* W1  = (const float*)d_in[2];
    const float* b1  = (const float*)d_in[3];
    const float* g1  = (const float*)d_in[4];
    const float* be1 = (const float*)d_in[5];
    const float* W2  = (const float*)d_in[6];
    const float* b2  = (const float*)d_in[7];
    const float* g2  = (const float*)d_in[8];
    const float* be2 = (const float*)d_in[9];

    float* out = (float*)d_out;

    // workspace layout
    char* ws = (char*)d_ws;
    float* h   = (float*)ws;                           // 25,600,000 B
    int*   cnt = (int*)(ws + 25600000);                //    400,000 B
    int*   bkt = (int*)(ws + 26000000);                // 12,800,000 B  (total 38.8 MB)

    const int E = in_sizes[1] / 2;

    zero_kernel<<<(N_NODES + 255) / 256, 256, 0, stream>>>(cnt, N_NODES);

    mlp_kernel<<<(N_NODES + 255) / 256, 256, 0, stream>>>(
        x, W1, b1, g1, be1, W2, b2, g2, be2, h, out);

    scatter_kernel<<<(E + 255) / 256, 256, 0, stream>>>(ei, h, cnt, bkt, out, E);

    // wave per node: 4 waves/block
    aggr_kernel<<<(N_NODES + 3) / 4, 256, 0, stream>>>(cnt, bkt, h, out);
}